// Round 6
// baseline (83.790 us; speedup 1.0000x reference)
//
#include <hip/hip_runtime.h>
#include <math.h>

// SubsetOperator (Gumbel top-K relaxation), B=4096 rows, N=8192 cols, K=8, TAU=1.
// Exp-domain transform: w = exp(s+g-M0); per iter: oh = w/sum; kh += oh;
// w = fma(-oh, w, w). One exp per element; K-loop is pure mul/fma + sum-reduce.
//
// Round-6: 1024 threads/block, 8 elems/thread (R1 geometry, R4 algorithm).
// Rationale: occupancy history shows 256-thr blocks cap at ~50% occupancy
// (~4 WGs/CU) while 1024-thr blocks reached 86%; with VALU at 23% and BW at
// 62% of ceiling the limiter is memory-level parallelism = resident waves.
// Minimal state (w[8]+kh[8] ~ 16 VGPR) keeps 2 blocks/CU = 32 waves resident.

#define BROWS 4096
#define NCOLS 8192
#define KITER 8
#define THREADS 1024
#define ELEMS (NCOLS / THREADS)   // 8
#define NWAVES (THREADS / 64)     // 16
#define M0 24.0f

typedef float f32x4 __attribute__((ext_vector_type(4)));

__global__ __launch_bounds__(THREADS)
void subset_op_kernel(const float* __restrict__ scores,
                      const float* __restrict__ g,
                      float* __restrict__ out) {
  const int tid = threadIdx.x;
  const int lane = tid & 63;
  const int wave = tid >> 6;
  const long long base = (long long)blockIdx.x * NCOLS + (long long)tid * 4;

  // ---- load (coalesced float4; elem j at tid*4 + (j>=4)*4096) ----
  const f32x4 s0 = *(const f32x4*)(scores + base);
  const f32x4 s1 = *(const f32x4*)(scores + base + 4096);
  const f32x4 g0 = *(const f32x4*)(g + base);
  const f32x4 g1 = *(const f32x4*)(g + base + 4096);

  float w[ELEMS], kh[ELEMS];
  w[0] = s0.x + g0.x; w[1] = s0.y + g0.y; w[2] = s0.z + g0.z; w[3] = s0.w + g0.w;
  w[4] = s1.x + g1.x; w[5] = s1.y + g1.y; w[6] = s1.z + g1.z; w[7] = s1.w + g1.w;

  float sum = 0.0f;
#pragma unroll
  for (int j = 0; j < ELEMS; ++j) {
    w[j] = __expf(w[j] - M0);
    sum += w[j];
    kh[j] = 0.0f;
  }

  __shared__ float red[2][NWAVES];

#pragma unroll 1
  for (int k = 0; k < KITER; ++k) {
    // ---- block sum: wave shfl-reduce -> LDS -> broadcast 16-wide sum ----
    float ps = sum;
#pragma unroll
    for (int off = 32; off > 0; off >>= 1) ps += __shfl_xor(ps, off);
    if (lane == 0) red[k & 1][wave] = ps;
    __syncthreads();
    const f32x4* rp = (const f32x4*)red[k & 1];
    const f32x4 rv = (rp[0] + rp[1]) + (rp[2] + rp[3]);
    const float tot = (rv.x + rv.y) + (rv.z + rv.w);
    const float inv = 1.0f / tot;

    // ---- onehot, khot accumulate, multiplicative mask, next partial sum ----
    sum = 0.0f;
#pragma unroll
    for (int j = 0; j < ELEMS; ++j) {
      const float oh = w[j] * inv;
      kh[j] += oh;
      w[j] = __builtin_fmaf(-oh, w[j], w[j]);
      sum += w[j];
    }
  }

  // ---- store khot (nontemporal: written once, never re-read) ----
  f32x4 o0, o1;
  o0.x = kh[0]; o0.y = kh[1]; o0.z = kh[2]; o0.w = kh[3];
  o1.x = kh[4]; o1.y = kh[5]; o1.z = kh[6]; o1.w = kh[7];
  __builtin_nontemporal_store(o0, (f32x4*)(out + base));
  __builtin_nontemporal_store(o1, (f32x4*)(out + base + 4096));
}

extern "C" void kernel_launch(void* const* d_in, const int* in_sizes, int n_in,
                              void* d_out, int out_size, void* d_ws, size_t ws_size,
                              hipStream_t stream) {
  const float* scores = (const float*)d_in[0];
  const float* g = (const float*)d_in[1];
  float* out = (float*)d_out;
  (void)in_sizes; (void)n_in; (void)out_size; (void)d_ws; (void)ws_size;

  subset_op_kernel<<<BROWS, THREADS, 0, stream>>>(scores, g, out);
}